// Round 1
// baseline (171.824 us; speedup 1.0000x reference)
//
#include <hip/hip_runtime.h>
#include <math.h>

#define IMG_H 512
#define IMG_W 512
#define NBATCH 8
#define TILE 32
#define GDIM 36            // TILE + 4 halo
#define NCH 9              // g channels: silu + 8 bases
#define NCONV 16

// ws layout (floats): [0,225) = Wc composed 5x5x9 kernel, [256, 256+1296) = W1 (16 x 9pos x 9ch)
#define WOFF_WC 0
#define WOFF_W1 256

// ---- g(x) = [silu(x), B0..B7(x)] : cubic B-spline bases on GRID (j-3)*0.4-1, j=0..11
__device__ __forceinline__ void eval_g(float x, float g[NCH]) {
    float b[11];
#pragma unroll
    for (int j = 0; j < 11; ++j) {
        float t0 = (float)(j - 3) * 0.4f - 1.0f;
        float t1 = (float)(j - 2) * 0.4f - 1.0f;
        b[j] = (x >= t0 && x < t1) ? 1.0f : 0.0f;
    }
#pragma unroll
    for (int k = 1; k <= 3; ++k) {
        float inv = 1.0f / (0.4f * (float)k);
#pragma unroll
        for (int j = 0; j < 11 - k; ++j) {
            float tj   = (float)(j - 3) * 0.4f - 1.0f;       // t_j
            float tjk1 = (float)(j + k - 2) * 0.4f - 1.0f;   // t_{j+k+1}
            b[j] = (x - tj) * inv * b[j] + (tjk1 - x) * inv * b[j + 1];
        }
    }
    g[0] = x / (1.0f + __expf(-x));   // silu
#pragma unroll
    for (int j = 0; j < 8; ++j) g[j + 1] = b[j];
}

// ---- prep: build W1 (KAN conv weights over g-channels) and composed 5x5 kernel Wc
__global__ void ConvKAN_prep(const float* __restrict__ bw, const float* __restrict__ sw,
                             const float* __restrict__ ss, const float* __restrict__ rw,
                             float* __restrict__ ws) {
    int t = threadIdx.x;
    // W1[(c*9 + i)*9 + ch], i = ky*3+kx
    for (int idx = t; idx < NCONV * 9 * NCH; idx += 256) {
        int ci = idx / NCH;      // c*9 + i
        int ch = idx % NCH;
        ws[WOFF_W1 + idx] = (ch == 0) ? bw[ci] : sw[ci * 8 + (ch - 1)] * ss[ci];
    }
    // Wc[(d*5+e)*9 + ch] = sum_c sum_{u,v} rw[c,u,v] * W1[c,ch,d-u,e-v]
    for (int idx = t; idx < 25 * NCH; idx += 256) {
        int de = idx / NCH, ch = idx % NCH;
        int d = de / 5, e = de % 5;
        float s = 0.0f;
        for (int c = 0; c < NCONV; ++c) {
            int ulo = d - 2 > 0 ? d - 2 : 0, uhi = d < 2 ? d : 2;
            int vlo = e - 2 > 0 ? e - 2 : 0, vhi = e < 2 ? e : 2;
            for (int u = ulo; u <= uhi; ++u)
                for (int v = vlo; v <= vhi; ++v) {
                    int i = (d - u) * 3 + (e - v);
                    float w1v = (ch == 0) ? bw[c * 9 + i]
                                          : sw[(c * 9 + i) * 8 + (ch - 1)] * ss[c * 9 + i];
                    s += rw[c * 9 + u * 3 + v] * w1v;
                }
        }
        ws[WOFF_WC + idx] = s;
    }
}

// ---- main: composed 5x5 conv over g-channels, g staged in LDS per 32x32 tile
__global__ __launch_bounds__(256) void ConvKAN_main(const float* __restrict__ x,
                                                    const float* __restrict__ wc,
                                                    const float* __restrict__ rb,
                                                    float* __restrict__ out) {
    __shared__ float gld[GDIM * GDIM * NCH];
    int tid = threadIdx.x;
    int b = blockIdx.z;
    int y0 = blockIdx.y * TILE, x0 = blockIdx.x * TILE;
    const float* xb = x + (size_t)b * IMG_H * IMG_W;

    for (int i = tid; i < GDIM * GDIM; i += 256) {
        int r = i / GDIM, c = i % GDIM;
        int gy = y0 + r - 2, gx = x0 + c - 2;
        float xv = (gy >= 0 && gy < IMG_H && gx >= 0 && gx < IMG_W) ? xb[gy * IMG_W + gx] : 0.0f;
        float g[NCH];
        eval_g(xv, g);   // OOB -> g(0): matches zero-padded im2col semantics
#pragma unroll
        for (int j = 0; j < NCH; ++j) gld[i * NCH + j] = g[j];
    }
    __syncthreads();

    int tx = tid & 31;
    int ty = tid >> 5;          // 0..7
    int r0 = ty * 4;            // first output row (tile coords) of this thread
    float bias = rb[0];
    float acc[4] = {bias, bias, bias, bias};

#pragma unroll
    for (int R = 0; R < 8; ++R) {       // g rows r0+R cover rows needed by pixels p=0..3
#pragma unroll
        for (int e = 0; e < 5; ++e) {
            const float* gp = &gld[((r0 + R) * GDIM + tx + e) * NCH];
            float gv[NCH];
#pragma unroll
            for (int ch = 0; ch < NCH; ++ch) gv[ch] = gp[ch];
#pragma unroll
            for (int p = 0; p < 4; ++p) {
                int d = R - p;
                if (d < 0 || d > 4) continue;          // compile-time eliminated
                const float* wp = &wc[(d * 5 + e) * NCH];
#pragma unroll
                for (int ch = 0; ch < NCH; ++ch)
                    acc[p] = fmaf(gv[ch], wp[ch], acc[p]);
            }
        }
    }
    float* ob = out + ((size_t)b * IMG_H + y0) * IMG_W + x0;
#pragma unroll
    for (int p = 0; p < 4; ++p)
        ob[(r0 + p) * IMG_W + tx] = acc[p];
}

// ---- border correction: subtract contributions of "virtual feat" at the 1-ring outside image
// (the composed conv implicitly includes them; true restore conv zero-pads feat)
__global__ void ConvKAN_corr(const float* __restrict__ x, const float* __restrict__ w1,
                             const float* __restrict__ rw, float* __restrict__ out) {
    int t = blockIdx.x * 256 + threadIdx.x;
    const int RING = 2 * (IMG_W + 2) + 2 * IMG_H;  // 2052
    if (t >= NBATCH * RING) return;
    int b = t / RING, r = t % RING;
    int fy, fx;
    if (r < IMG_W + 2)            { fy = -1;            fx = r - 1; }
    else if (r < 2 * (IMG_W + 2)) { fy = IMG_H;         fx = (r - (IMG_W + 2)) - 1; }
    else if (r < 2 * (IMG_W + 2) + IMG_H) { fy = r - 2 * (IMG_W + 2); fx = -1; }
    else                          { fy = r - (2 * (IMG_W + 2) + IMG_H); fx = IMG_W; }

    const float* xb = x + (size_t)b * IMG_H * IMG_W;
    float fc[NCONV];
#pragma unroll
    for (int c = 0; c < NCONV; ++c) fc[c] = 0.0f;

#pragma unroll
    for (int a = 0; a < 3; ++a) {
#pragma unroll
        for (int bb = 0; bb < 3; ++bb) {
            int gy = fy + a - 1, gx = fx + bb - 1;
            float xv = (gy >= 0 && gy < IMG_H && gx >= 0 && gx < IMG_W) ? xb[gy * IMG_W + gx] : 0.0f;
            float g[NCH];
            eval_g(xv, g);
            int i = a * 3 + bb;
#pragma unroll
            for (int c = 0; c < NCONV; ++c) {
                const float* wp = &w1[(c * 9 + i) * NCH];
                float s = 0.0f;
#pragma unroll
                for (int ch = 0; ch < NCH; ++ch) s += wp[ch] * g[ch];
                fc[c] += s;
            }
        }
    }
    // scatter: out(fy-u+1, fx-v+1) -= sum_c rw[c,u,v]*fc[c]
#pragma unroll
    for (int u = 0; u < 3; ++u) {
#pragma unroll
        for (int v = 0; v < 3; ++v) {
            int ty = fy - (u - 1), tx2 = fx - (v - 1);
            if (ty >= 0 && ty < IMG_H && tx2 >= 0 && tx2 < IMG_W) {
                float s = 0.0f;
#pragma unroll
                for (int c = 0; c < NCONV; ++c) s += rw[c * 9 + u * 3 + v] * fc[c];
                atomicAdd(&out[((size_t)b * IMG_H + ty) * IMG_W + tx2], -s);
            }
        }
    }
}

extern "C" void kernel_launch(void* const* d_in, const int* in_sizes, int n_in,
                              void* d_out, int out_size, void* d_ws, size_t ws_size,
                              hipStream_t stream) {
    const float* x  = (const float*)d_in[0];
    const float* bw = (const float*)d_in[1];
    const float* sw = (const float*)d_in[2];
    const float* ss = (const float*)d_in[3];
    const float* rw = (const float*)d_in[4];
    const float* rb = (const float*)d_in[5];
    float* out = (float*)d_out;
    float* ws  = (float*)d_ws;

    ConvKAN_prep<<<1, 256, 0, stream>>>(bw, sw, ss, rw, ws);
    ConvKAN_main<<<dim3(IMG_W / TILE, IMG_H / TILE, NBATCH), 256, 0, stream>>>(
        x, ws + WOFF_WC, rb, out);
    const int RING = 2 * (IMG_W + 2) + 2 * IMG_H;
    int nthr = NBATCH * RING;
    ConvKAN_corr<<<(nthr + 255) / 256, 256, 0, stream>>>(x, ws + WOFF_W1, rw, out);
}